// Round 15
// baseline (951.383 us; speedup 1.0000x reference)
//
#include <hip/hip_runtime.h>
#include <cstddef>
#include <cstdint>

#define D_MODEL 1024
#define D_INNER 2048
#define DT_RANK 64
#define D_STATE 8
#define NLAYERS 4
#define BATCH 2
#define SEQ 1024
#define M_ROWS (BATCH*SEQ)   /* 2048 */
#define VOCAB 32000
#define XPAD 128             /* x_proj N padded 80 -> 128 */
#define NC 32                /* scan chunks */
#define LC 32                /* chunk length (NC*LC == SEQ) */
#define XSK 16               /* x_proj split-K factor */
#define OSK 2                /* out_proj split-K factor */

typedef __attribute__((ext_vector_type(8))) short short8;
typedef __attribute__((ext_vector_type(4))) float f32x4;

#define GPTR(p) (const __attribute__((address_space(1))) void*)(p)
#define LPTR(p) (__attribute__((address_space(3))) void*)(p)

__device__ __forceinline__ float sigmoidf_(float x) { return 1.f / (1.f + __expf(-x)); }

__device__ __forceinline__ unsigned short f2bf(float f) {
    unsigned u = __float_as_uint(f);
    u += 0x7fffu + ((u >> 16) & 1u);         // round-to-nearest-even
    return (unsigned short)(u >> 16);
}
__device__ __forceinline__ float bf2f(unsigned short u) {
    return __uint_as_float((unsigned)u << 16);
}

// ---------------------------------------------------------------------------
// Merged weight cast: all 5 regions in ONE launch (region-dispatch on index).
// ---------------------------------------------------------------------------
#define N4_IN  (NLAYERS * 2 * D_INNER * D_MODEL / 4)
#define N4_OUT (NLAYERS * D_MODEL * D_INNER / 4)
#define N4_FC  (VOCAB * D_MODEL / 4)
#define N4_DT  (NLAYERS * D_INNER * DT_RANK / 4)
#define N4_XP  (NLAYERS * XPAD * D_INNER / 4)
#define CAST_O1 (N4_IN)
#define CAST_O2 (CAST_O1 + N4_OUT)
#define CAST_O3 (CAST_O2 + N4_FC)
#define CAST_O4 (CAST_O3 + N4_DT)
#define CAST_TOT (CAST_O4 + N4_XP)

__device__ __forceinline__ void cast4(const float* __restrict__ in,
                                      unsigned short* __restrict__ out, int j)
{
    float4 v = ((const float4*)in)[j];
    ushort4 o;
    o.x = f2bf(v.x); o.y = f2bf(v.y); o.z = f2bf(v.z); o.w = f2bf(v.w);
    ((ushort4*)out)[j] = o;
}

__global__ __launch_bounds__(256) void cast_all(const float* __restrict__ in_proj,
                                                const float* __restrict__ out_proj,
                                                const float* __restrict__ fc_w,
                                                const float* __restrict__ dt_w,
                                                const float* __restrict__ x_proj,
                                                unsigned short* __restrict__ wb_in,
                                                unsigned short* __restrict__ wb_out,
                                                unsigned short* __restrict__ wb_fc,
                                                unsigned short* __restrict__ wb_dt,
                                                unsigned short* __restrict__ wb_x)
{
    int i = blockIdx.x * 256 + threadIdx.x;
    if (i < CAST_O1) {
        cast4(in_proj, wb_in, i);
    } else if (i < CAST_O2) {
        cast4(out_proj, wb_out, i - CAST_O1);
    } else if (i < CAST_O3) {
        cast4(fc_w, wb_fc, i - CAST_O2);
    } else if (i < CAST_O4) {
        cast4(dt_w, wb_dt, i - CAST_O3);
    } else if (i < CAST_TOT) {
        int i2 = i - CAST_O4;
        int col4 = i2 & (D_INNER / 4 - 1);
        int row = (i2 >> 9) & (XPAD - 1);
        int layer = i2 >> 16;
        ushort4 o = {0, 0, 0, 0};
        if (row < 80) {
            float4 v = ((const float4*)(x_proj + ((size_t)layer * 80 + row) * D_INNER))[col4];
            o.x = f2bf(v.x); o.y = f2bf(v.y); o.z = f2bf(v.z); o.w = f2bf(v.w);
        }
        ((ushort4*)wb_x)[i2] = o;
    }
}

// ---------------------------------------------------------------------------
// Embedding gather -> x (fp32) and xb (bf16)
// ---------------------------------------------------------------------------
__global__ __launch_bounds__(256) void gather_kernel(const int* __restrict__ ids,
                                                     const float* __restrict__ embed,
                                                     float* __restrict__ x,
                                                     unsigned short* __restrict__ xb)
{
    int m = blockIdx.x;
    int t = threadIdx.x;
    int id = ids[m];
    float4 v = ((const float4*)(embed + (size_t)id * D_MODEL))[t];
    ((float4*)(x + (size_t)m * D_MODEL))[t] = v;
    ushort4 o;
    o.x = f2bf(v.x); o.y = f2bf(v.y); o.z = f2bf(v.z); o.w = f2bf(v.w);
    ((ushort4*)(xb + (size_t)m * D_MODEL))[t] = o;
}

// ---------------------------------------------------------------------------
// bf16 MFMA GEMM  C[M,N] = A[M,K] * B[N,K]^T
// 128x128 tile, BK=32, 4 waves. Double-buffered LDS, counted-vmcnt pipeline.
// EPI: 0 fp32 (+splitK z-offset) | 1 bf16 | 2 fp32 +bias | 3 bf16 softplus(v+bias)
// ---------------------------------------------------------------------------
template<int EPI>
__global__ __launch_bounds__(256) void gemm_bf16_nt(const unsigned short* __restrict__ A, int lda,
                                                    const unsigned short* __restrict__ B, int ldb,
                                                    void* __restrict__ Cv, int ldc,
                                                    int K, const float* __restrict__ bias)
{
    __shared__ unsigned short As[2][128 * 32];
    __shared__ unsigned short Bs[2][128 * 32];
    const int tid = threadIdx.x;

    const int gm = gridDim.x;
    const int bid = blockIdx.y * gm + blockIdx.x;
    const int q = (gm * gridDim.y) >> 3;           // nwg % 8 == 0 guaranteed
    const int swz = (bid & 7) * q + (bid >> 3);
    const int bm = (swz % gm) * 128, bn = (swz / gm) * 128;

    const int wid = tid >> 6, lane = tid & 63;
    const int wm = (wid >> 1) * 64, wn = (wid & 1) * 64;
    const int lrow = lane & 15, lkg = lane >> 4;

    const int srow = tid >> 2;                               // 0..63
    const int ksrc = ((tid & 3) ^ ((srow >> 1) & 3)) * 8;    // elems, const/thread
    const size_t kz = (size_t)blockIdx.z * K;
    const unsigned short* Ag = A + (size_t)(bm + srow) * lda + kz + ksrc;
    const unsigned short* Bg = B + (size_t)(bn + srow) * ldb + kz + ksrc;
    const size_t r64a = (size_t)64 * lda;
    const size_t r64b = (size_t)64 * ldb;

#define STAGE(buf, koff)                                                                              \
    do {                                                                                              \
        __builtin_amdgcn_global_load_lds(GPTR(Ag + (koff)),        LPTR(&As[buf][tid * 8]), 16, 0, 0);\
        __builtin_amdgcn_global_load_lds(GPTR(Ag + r64a + (koff)), LPTR(&As[buf][2048 + tid * 8]), 16, 0, 0);\
        __builtin_amdgcn_global_load_lds(GPTR(Bg + (koff)),        LPTR(&Bs[buf][tid * 8]), 16, 0, 0);\
        __builtin_amdgcn_global_load_lds(GPTR(Bg + r64b + (koff)), LPTR(&Bs[buf][2048 + tid * 8]), 16, 0, 0);\
    } while (0)

    f32x4 acc[4][4];
    #pragma unroll
    for (int i = 0; i < 4; ++i)
        #pragma unroll
        for (int j = 0; j < 4; ++j)
            acc[i][j] = f32x4{0.f, 0.f, 0.f, 0.f};

    STAGE(0, 0);                      // prologue

    int cur = 0;
    for (int k0 = 0; k0 < K; k0 += 32) {
        if (k0 + 32 < K) {
            STAGE(cur ^ 1, k0 + 32);                             // next tile in flight
            asm volatile("s_waitcnt vmcnt(4)" ::: "memory");     // cur's 4 landed
        } else {
            asm volatile("s_waitcnt vmcnt(0)" ::: "memory");     // final drain
        }
        __builtin_amdgcn_s_barrier();          // publish cur to all waves
        __builtin_amdgcn_sched_barrier(0);     // pin: no hoisting above the wait

        short8 af[4], bf[4];
        #pragma unroll
        for (int i = 0; i < 4; ++i) {
            int ra = wm + 16 * i + lrow;
            int pa = lkg ^ ((ra >> 1) & 3);
            af[i] = *(const short8*)(&As[cur][ra * 32 + pa * 8]);
            int rb = wn + 16 * i + lrow;
            int pb = lkg ^ ((rb >> 1) & 3);
            bf[i] = *(const short8*)(&Bs[cur][rb * 32 + pb * 8]);
        }
        __builtin_amdgcn_s_setprio(1);
        #pragma unroll
        for (int i = 0; i < 4; ++i)
            #pragma unroll
            for (int j = 0; j < 4; ++j)
                acc[i][j] = __builtin_amdgcn_mfma_f32_16x16x32_bf16(af[i], bf[j], acc[i][j], 0, 0, 0);
        __builtin_amdgcn_s_setprio(0);

        __builtin_amdgcn_s_barrier();          // all reads of cur done before overwrite
        cur ^= 1;
    }
#undef STAGE

    const int crow = bm + wm + lkg * 4;
    const int ccol = bn + wn + lrow;
    #pragma unroll
    for (int i = 0; i < 4; ++i) {
        #pragma unroll
        for (int j = 0; j < 4; ++j) {
            float bv = (EPI == 2 || EPI == 3) ? bias[ccol + 16 * j] : 0.f;
            #pragma unroll
            for (int r = 0; r < 4; ++r) {
                float v = acc[i][j][r] + bv;
                size_t off = (size_t)(crow + 16 * i + r) * ldc + ccol + 16 * j;
                if (EPI == 0) {
                    ((float*)Cv)[(size_t)blockIdx.z * M_ROWS * ldc + off] = v;
                } else if (EPI == 2) {
                    ((float*)Cv)[off] = v;
                } else {
                    if (EPI == 3) v = (v > 20.f) ? v : log1pf(__expf(v));
                    ((unsigned short*)Cv)[off] = f2bf(v);
                }
            }
        }
    }
}

// ---------------------------------------------------------------------------
// 8-phase 256x256 GEMM, m201 template + one-phase A-read pipelining.
// 512 thr = 8 waves (2M x 4N); 2 K-tiles (BK=64)/iter; LDS 128 KiB.
// Stage slots (1 half-tile/phase): P1:A(T1)h1 P2:B(T0+2)h0 P3:B(T0+2)h1
//   P4:A(T0+2)h0 P5:A(T0+2)h1 P6:B(T1+2)h0 P7:B(T1+2)h1 P8:A(T1+2)h0
// vmcnt(6) ONLY at P4/P8. a0-fragment reads are pipelined one phase ahead:
// issued POST-barrier at P4/P8 (data provably landed for ALL waves only
// after the barrier that follows each wave's own vmcnt), overlapping the
// register-only MFMA Q(1,0). Pre-barrier reads per phase: 4,4,8,-,4,4,8,-.
// Buffer safety re-verified: every stage >=1 end-barrier after its half's
// last read; a-reads complete >=3 barriers before their region restages.
// T2 swizzle p = u ^ (row&7); inverse-swizzled global source (rule #21).
// ---------------------------------------------------------------------------
__device__ __forceinline__ void rd_a8(const unsigned short* S, int base, int lrow, int lkg, short8 a[4][2]) {
    #pragma unroll
    for (int i = 0; i < 4; ++i)
        #pragma unroll
        for (int kk = 0; kk < 2; ++kk) {
            int row = base + i * 16 + lrow;
            int p = (kk * 4 + lkg) ^ (lrow & 7);
            a[i][kk] = *(const short8*)(S + row * 64 + p * 8);
        }
}
__device__ __forceinline__ void rd_b4(const unsigned short* S, int base, int lrow, int lkg, short8 b[2][2]) {
    #pragma unroll
    for (int j = 0; j < 2; ++j)
        #pragma unroll
        for (int kk = 0; kk < 2; ++kk) {
            int row = base + j * 16 + lrow;
            int p = (kk * 4 + lkg) ^ (lrow & 7);
            b[j][kk] = *(const short8*)(S + row * 64 + p * 8);
        }
}

__global__ __launch_bounds__(512) void gemm_bf16_8ph(const unsigned short* __restrict__ A, int lda,
                                                     const unsigned short* __restrict__ B, int ldb,
                                                     float* __restrict__ C, int ldc,
                                                     int K, const float* __restrict__ bias)
{
    __shared__ unsigned short As[2][256 * 64];
    __shared__ unsigned short Bs[2][256 * 64];
    const int tid = threadIdx.x;

    const int gm = gridDim.x;
    const int bid = blockIdx.y * gm + blockIdx.x;
    const int q = (gm * gridDim.y) >> 3;
    const int swz = (bid & 7) * q + (bid >> 3);
    const int bm = (swz % gm) * 256, bn = (swz / gm) * 256;

    const int wid = tid >> 6, lane = tid & 63;
    const int wr = wid >> 2, wc = wid & 3;
    const int arow0 = wr * 128;                 // wave's A half
    const int b0r = wc * 32, b1r = 128 + wc * 32;
    const int lrow = lane & 15, lkg = lane >> 4;

    const int sg = tid >> 3, su = tid & 7;      // staging row-in-64 / unit
    const int ksrc = (su ^ (sg & 7)) * 8;       // inverse-swizzled global src
    const unsigned short* Ag = A + (size_t)(bm + sg) * lda + ksrc;
    const unsigned short* Bg = B + (size_t)(bn + sg) * ldb + ksrc;

#define STG_A_H(buf, kt, h) do {                                                                   \
    __builtin_amdgcn_global_load_lds(GPTR(Ag + (size_t)(kt) * 64 + (size_t)((h) * 128) * lda),     \
                                     LPTR(&As[buf][(h) * 8192 + tid * 8]), 16, 0, 0);              \
    __builtin_amdgcn_global_load_lds(GPTR(Ag + (size_t)(kt) * 64 + (size_t)((h) * 128 + 64) * lda),\
                                     LPTR(&As[buf][(h) * 8192 + 4096 + tid * 8]), 16, 0, 0);       \
} while (0)
#define STG_B_H(buf, kt, h) do {                                                                   \
    __builtin_amdgcn_global_load_lds(GPTR(Bg + (size_t)(kt) * 64 + (size_t)((h) * 128) * ldb),     \
                                     LPTR(&Bs[buf][(h) * 8192 + tid * 8]), 16, 0, 0);              \
    __builtin_amdgcn_global_load_lds(GPTR(Bg + (size_t)(kt) * 64 + (size_t)((h) * 128 + 64) * ldb),\
                                     LPTR(&Bs[buf][(h) * 8192 + 4096 + tid * 8]), 16, 0, 0);       \
} while (0)
#define WAITN(n) asm volatile("s_waitcnt vmcnt(" #n ")" ::: "memory")
#define PBAR() __builtin_amdgcn_s_barrier()
#define SBAR() __builtin_amdgcn_sched_barrier(0)
#define MFMA_Q(QA, BH, AARR, BARR) do {                                                            \
    __builtin_amdgcn_s_setprio(1);                                                                 \
    _Pragma("unroll") for (int i = 0; i < 4; ++i)                                                  \
    _Pragma("unroll") for (int j = 0; j < 2; ++j)                                                  \
    _Pragma("unroll") for (int kk = 0; kk < 2; ++kk)                                               \
        acc[(QA) * 4 + i][(BH) * 2 + j] =                                                          \
            __builtin_amdgcn_mfma_f32_16x16x32_bf16(AARR[i][kk], BARR[j][kk],                      \
                                                    acc[(QA) * 4 + i][(BH) * 2 + j], 0, 0, 0);     \
    __builtin_amdgcn_s_setprio(0);                                                                 \
} while (0)

    f32x4 acc[8][4];
    #pragma unroll
    for (int i = 0; i < 8; ++i)
        #pragma unroll
        for (int j = 0; j < 4; ++j)
            acc[i][j] = f32x4{0.f, 0.f, 0.f, 0.f};

    short8 aA[4][2], aB[4][2], b[2][2], b0s[2][2];
    const int NT = K >> 6;        // 16 K-tiles
    const int NI = NT >> 1;       // 8 iterations

    // prologue: T0 fully, then A(T1)h0, B(T1)h0, B(T1)h1; wait T0 landed;
    // post-barrier read a0(T0) -> aA (pipelined into P1).
    STG_A_H(0, 0, 0); STG_A_H(0, 0, 1); STG_B_H(0, 0, 0); STG_B_H(0, 0, 1);
    STG_A_H(1, 1, 0); STG_B_H(1, 1, 0); STG_B_H(1, 1, 1);
    WAITN(6);
    PBAR();
    rd_a8(As[0], arow0, lrow, lkg, aA);

    for (int it = 0; it < NI; ++it) {
        const int T1 = 2 * it + 1;
        const int T0n = 2 * it + 2, T1n = 2 * it + 3;   // prefetch targets
        const bool more = (it + 1 < NI);

        // P1: stage A(T1)h1; read b0(T0)->b0s; Q(0,0) uses aA (read prev P8)
        STG_A_H(1, T1, 1);
        rd_b4(Bs[0], b0r, lrow, lkg, b0s);
        PBAR(); SBAR();
        MFMA_Q(0, 0, aA, b0s);
        PBAR();
        // P2: stage B(T0+2)h0 (Bs[0]h0 free since P1); read b1(T0); Q(0,1)
        if (more) STG_B_H(0, T0n, 0);
        rd_b4(Bs[0], b1r, lrow, lkg, b);
        PBAR(); SBAR();
        MFMA_Q(0, 1, aA, b);
        PBAR();
        // P3: stage B(T0+2)h1; read a1(T0)->aB; Q(1,1)
        if (more) STG_B_H(0, T0n, 1);
        rd_a8(As[0], arow0 + 64, lrow, lkg, aB);
        PBAR(); SBAR();
        MFMA_Q(1, 1, aB, b);
        PBAR();
        // P4: stage A(T0+2)h0; WAIT(6) forces slot-P1 (A(T1)h1) + older landed.
        //     POST-barrier: read a0(T1)->aA (valid for all waves after PBAR),
        //     overlapping register-only Q(1,0).
        if (more) { STG_A_H(0, T0n, 0); WAITN(6); } else { WAITN(0); }
        PBAR(); SBAR();
        rd_a8(As[1], arow0, lrow, lkg, aA);
        MFMA_Q(1, 0, aB, b0s);
        PBAR();
        // P5: stage A(T0+2)h1; read b0(T1)->b0s; Q(0,0) uses aA (read P4)
        if (more) STG_A_H(0, T0n, 1);
        rd_b4(Bs[1], b0r, lrow, lkg, b0s);
        PBAR(); SBAR();
        MFMA_Q(0, 0, aA, b0s);
        PBAR();
        // P6: stage B(T1+2)h0; read b1(T1); Q(0,1)
        if (more) STG_B_H(1, T1n, 0);
        rd_b4(Bs[1], b1r, lrow, lkg, b);
        PBAR(); SBAR();
        MFMA_Q(0, 1, aA, b);
        PBAR();
        // P7: stage B(T1+2)h1; read a1(T1)->aB; Q(1,1)
        if (more) STG_B_H(1, T1n, 1);
        rd_a8(As[1], arow0 + 64, lrow, lkg, aB);
        PBAR(); SBAR();
        MFMA_Q(1, 1, aB, b);
        PBAR();
        // P8: stage A(T1+2)h0; WAIT(6) forces slots P2..P5 (T0+2 data) landed.
        //     POST-barrier: read a0(T0+2)->aA for next iter's P1; Q(1,0).
        if (more) { STG_A_H(1, T1n, 0); WAITN(6); } else { WAITN(0); }
        PBAR(); SBAR();
        if (more) rd_a8(As[0], arow0, lrow, lkg, aA);
        MFMA_Q(1, 0, aB, b0s);
        PBAR();
    }
#undef STG_A_H
#undef STG_B_H
#undef WAITN
#undef PBAR
#undef SBAR
#undef MFMA_Q

    // C write: row = bm + arow0 + i*16 + lkg*4 + r;
    // col(j) = bn + (j>>1)*128 + wc*32 + (j&1)*16 + lrow
    const int crow = bm + arow0 + lkg * 4;
    #pragma unroll
    for (int i = 0; i < 8; ++i) {
        #pragma unroll
        for (int j = 0; j < 4; ++j) {
            int ccol = bn + (j >> 1) * 128 + wc * 32 + (j & 1) * 16 + lrow;
            float bv = bias[ccol];
            float* Cp = C + (size_t)(crow + 16 * i) * ldc + ccol;
            #pragma unroll
            for (int r = 0; r < 4; ++r)
                Cp[(size_t)r * ldc] = acc[i][j][r] + bv;
        }
    }
}

// ---------------------------------------------------------------------------
// Reduce XSK split-K partials -> xdbl (fp32) + xdbl_b (bf16)
// ---------------------------------------------------------------------------
__global__ __launch_bounds__(256) void reduce_xdbl(const float* __restrict__ part,
                                                   float* __restrict__ xdbl,
                                                   unsigned short* __restrict__ xdbl_b)
{
    int i = blockIdx.x * 256 + threadIdx.x;     // over 2048*128/4 = 65536
    float4 s = ((const float4*)part)[i];
    #pragma unroll
    for (int z = 1; z < XSK; ++z) {
        float4 v = ((const float4*)part)[(size_t)z * (M_ROWS * XPAD / 4) + i];
        s.x += v.x; s.y += v.y; s.z += v.z; s.w += v.w;
    }
    ((float4*)xdbl)[i] = s;
    ushort4 o;
    o.x = f2bf(s.x); o.y = f2bf(s.y); o.z = f2bf(s.z); o.w = f2bf(s.w);
    ((ushort4*)xdbl_b)[i] = o;
}

// ---------------------------------------------------------------------------
// Causal depthwise conv1d (k=4) + bias + SiLU; bf16 in (xzb) -> bf16 out (xcb)
// ---------------------------------------------------------------------------
__global__ __launch_bounds__(256) void conv_silu_kernel(const unsigned short* __restrict__ xzb,
                                                        const float* __restrict__ cw,
                                                        const float* __restrict__ cb,
                                                        unsigned short* __restrict__ xcb)
{
    int idx = blockIdx.x * 256 + threadIdx.x;
    int d = idx & (D_INNER - 1);
    int m = idx >> 11;
    int l = m & (SEQ - 1);
    int b = m >> 10;
    float w0 = cw[d * 4 + 0], w1 = cw[d * 4 + 1], w2 = cw[d * 4 + 2], w3 = cw[d * 4 + 3];
    float s = cb[d];
    const unsigned short* base = xzb + ((size_t)b * SEQ) * (2 * D_INNER) + d;
    if (l - 3 >= 0) s += bf2f(base[(size_t)(l - 3) * (2 * D_INNER)]) * w0;
    if (l - 2 >= 0) s += bf2f(base[(size_t)(l - 2) * (2 * D_INNER)]) * w1;
    if (l - 1 >= 0) s += bf2f(base[(size_t)(l - 1) * (2 * D_INNER)]) * w2;
    s += bf2f(base[(size_t)l * (2 * D_INNER)]) * w3;
    float v = s * sigmoidf_(s);
    xcb[(size_t)m * D_INNER + d] = f2bf(v);
}

// ---------------------------------------------------------------------------
// Chunk-parallel selective scan (linear recurrence decomposition).
// 1 d per thread (latency-bound: maximize wave count).
// ---------------------------------------------------------------------------
__global__ __launch_bounds__(256) void scan_partial(const unsigned short* __restrict__ dtb,
                                                    const float* __restrict__ xdbl,
                                                    const unsigned short* __restrict__ xcb,
                                                    const float* __restrict__ A_log,
                                                    float* __restrict__ H,
                                                    float* __restrict__ P)
{
    const int tid = threadIdx.x;
    const int b = blockIdx.x & 1;
    const int c = (blockIdx.x >> 1) & (NC - 1);
    const int d = ((blockIdx.x >> 6) << 8) + tid;

    __shared__ float Bsm[LC][8];
    {
        int r = tid >> 3, n = tid & 7;
        Bsm[r][n] = xdbl[(size_t)(b * SEQ + c * LC + r) * XPAD + DT_RANK + n];
    }
    __syncthreads();

    float An[8];
    #pragma unroll
    for (int n = 0; n < 8; ++n) An[n] = -__expf(A_log[d * 8 + n]);
    float h[8] = {0.f,0.f,0.f,0.f,0.f,0.f,0.f,0.f};
    float p[8] = {1.f,1.f,1.f,1.f,1.f,1.f,1.f,1.f};

    const unsigned short* dtp = dtb + (size_t)(b * SEQ + c * LC) * D_INNER + d;
    const unsigned short* xcp = xcb + (size_t)(b * SEQ + c * LC) * D_INNER + d;
    for (int l = 0; l < LC; ++l) {
        float dtv = bf2f(dtp[(size_t)l * D_INNER]);
        float ux  = dtv * bf2f(xcp[(size_t)l * D_INNER]);
        #pragma unroll
        for (int n = 0; n < 8; ++n) {
            float dA = __expf(dtv * An[n]);
            h[n] = dA * h[n] + Bsm[l][n] * ux;
            p[n] *= dA;
        }
    }
    size_t base = (size_t)((b * NC + c) * 8) * D_INNER + d;
    #pragma unroll
    for (int n = 0; n < 8; ++n) {
        H[base + (size_t)n * D_INNER] = h[n];
        P[base + (size_t)n * D_INNER] = p[n];
    }
}

__global__ __launch_bounds__(256) void scan_combine(const float* __restrict__ H,
                                                    float* __restrict__ P /* -> h0 */)
{
    int idx = blockIdx.x * 256 + threadIdx.x;   // 32768 = 2*8*2048
    int d = idx & (D_INNER - 1);
    int n = (idx >> 11) & 7;
    int b = idx >> 14;
    float hp = 0.f;
    for (int c = 0; c < NC; ++c) {
        size_t base = (size_t)((b * NC + c) * 8 + n) * D_INNER + d;
        float Pv = P[base], Hv = H[base];
        P[base] = hp;
        hp = Pv * hp + Hv;
    }
}

__global__ __launch_bounds__(256) void scan_final(const unsigned short* __restrict__ dtb,
                                                  const float* __restrict__ xdbl,
                                                  const unsigned short* __restrict__ xcb,
                                                  const unsigned short* __restrict__ xzb,
                                                  const float* __restrict__ A_log,
                                                  const float* __restrict__ Dp,
                                                  const float* __restrict__ h0,
                                                  unsigned short* __restrict__ yb)
{
    const int tid = threadIdx.x;
    const int b = blockIdx.x & 1;
    const int c = (blockIdx.x >> 1) & (NC - 1);
    const int d = ((blockIdx.x >> 6) << 8) + tid;

    __shared__ float Bsm[LC][8];
    __shared__ float Csm[LC][8];
    {
        int r = tid >> 3, n = tid & 7;
        size_t xrow = (size_t)(b * SEQ + c * LC + r) * XPAD;
        Bsm[r][n] = xdbl[xrow + DT_RANK + n];
        Csm[r][n] = xdbl[xrow + DT_RANK + 8 + n];
    }
    __syncthreads();

    float An[8], h[8];
    size_t base = (size_t)((b * NC + c) * 8) * D_INNER + d;
    #pragma unroll
    for (int n = 0; n < 8; ++n) {
        An[n] = -__expf(A_log[d * 8 + n]);
        h[n] = h0[base + (size_t)n * D_INNER];
    }
    const float Dv = Dp[d];

    const unsigned short* dtp = dtb + (size_t)(b * SEQ + c * LC) * D_INNER + d;
    const unsigned short* xcp = xcb + (size_t)(b * SEQ + c * LC) * D_INNER + d;
    const unsigned short* zp  = xzb + (size_t)(b * SEQ + c * LC) * (2 * D_INNER) + D_INNER + d;
    unsigned short* ybp = yb + (size_t)(b * SEQ + c * LC) * D_INNER + d;

    for (int l = 0; l < LC; ++l) {
        float dtv = bf2f(dtp[(size_t)l * D_INNER]);
        float xcv = bf2f(xcp[(size_t)l * D_INNER]);
        float zv  = bf2f(zp[(size_t)l * (2 * D_INNER)]);
        float ux = dtv * xcv;
        float acc = 0.f;
        #pragma unroll
        for (int n = 0; n < 8; ++n) {
            float dA = __expf(dtv * An[n]);
            h[n] = dA * h[n] + Bsm[l][n] * ux;
            acc += h[n] * Csm[l][n];
        }
        float yv = (acc + xcv * Dv) * (zv * sigmoidf_(zv));
        ybp[(size_t)l * D_INNER] = f2bf(yv);
    }
}

// ---------------------------------------------------------------------------
// LayerNorm (1024). NEXTRA extras summed with xin. Emits fp32 + bf16.
// ---------------------------------------------------------------------------
template<int NEXTRA>
__global__ __launch_bounds__(256) void ln_kernel(const float* __restrict__ e0,
                                                 const float* __restrict__ e1,
                                                 const float* __restrict__ xin,
                                                 float* __restrict__ xout,
                                                 unsigned short* __restrict__ xbout,
                                                 const float* __restrict__ g,
                                                 const float* __restrict__ bb)
{
    int m = blockIdx.x;
    int t = threadIdx.x;
    float4 v = ((const float4*)(xin + (size_t)m * D_MODEL))[t];
    if (NEXTRA >= 1) {
        float4 e = ((const float4*)(e0 + (size_t)m * D_MODEL))[t];
        v.x += e.x; v.y += e.y; v.z += e.z; v.w += e.w;
    }
    if (NEXTRA >= 2) {
        float4 e = ((const float4*)(e1 + (size_t)m * D_MODEL))[t];
        v.x += e.x; v.y += e.y; v.z += e.z; v.w += e.w;
    }
    float s  = v.x + v.y + v.z + v.w;
    float s2 = v.x * v.x + v.y * v.y + v.z * v.z + v.w * v.w;
    for (int off = 32; off; off >>= 1) {
        s  += __shfl_down(s, off);
        s2 += __shfl_down(s2, off);
    }
    __shared__ float red[8];
    int wid = t >> 6, lane = t & 63;
    if (lane == 0) { red[wid] = s; red[wid + 4] = s2; }
    __syncthreads();
    if (t == 0) {
        float a  = red[0] + red[1] + red[2] + red[3];
        float b2 = red[4] + red[5] + red[6] + red[7];
        float mu = a * (1.f / D_MODEL);
        red[0] = mu;
        red[4] = b2 * (1.f / D_MODEL) - mu * mu;
    }
    __syncthreads();
    float mu = red[0];
    float rs = rsqrtf(red[4] + 1e-5f);
    float4 gg = ((const float4*)g)[t];
    float4 bv = ((const float4*)bb)[t];
    float4 o;
    o.x = (v.x - mu) * rs * gg.x + bv.x;
    o.y = (v.y - mu) * rs * gg.y + bv.y;
    o.z = (v.z - mu) * rs * gg.z + bv.z;
    o.w = (v.w - mu) * rs * gg.w + bv.w;
    ((float4*)(xout + (size_t)m * D_MODEL))[t] = o;
    ushort4 ob;
    ob.x = f2bf(o.x); ob.y = f2bf(o.y); ob.z = f2bf(o.z); ob.w = f2bf(o.w);
    ((ushort4*)(xbout + (size_t)m * D_MODEL))[t] = ob;
}

// ---------------------------------------------------------------------------
extern "C" void kernel_launch(void* const* d_in, const int* in_sizes, int n_in,
                              void* d_out, int out_size, void* d_ws, size_t ws_size,
                              hipStream_t stream)
{
    const int*   ids      = (const int*)d_in[0];
    const float* embed    = (const float*)d_in[1];
    const float* in_proj  = (const float*)d_in[2];
    const float* conv_w   = (const float*)d_in[3];
    const float* conv_b   = (const float*)d_in[4];
    const float* x_proj   = (const float*)d_in[5];
    const float* dt_w     = (const float*)d_in[6];
    const float* dt_b     = (const float*)d_in[7];
    const float* A_log    = (const float*)d_in[8];
    const float* Dp       = (const float*)d_in[9];
    const float* out_proj = (const float*)d_in[10];
    const float* ln_g     = (const float*)d_in[11];
    const float* ln_b     = (const float*)d_in[12];
    const float* fn_g     = (const float*)d_in[13];
    const float* fn_b     = (const float*)d_in[14];
    const float* fc_w     = (const float*)d_in[15];
    const float* fc_b     = (const float*)d_in[16];
    float* logits = (float*)d_out;

    // ---- workspace layout (fp32 first, then bf16) ----
    float* ws = (float*)d_ws;
    float* x     = ws;                                   // 2048*1024
    float* xdbl  = x + (size_t)M_ROWS * D_MODEL;         // 2048*128
    float* tmp   = xdbl + (size_t)M_ROWS * XPAD;         // 2048*1024 (H/P alias)
    float* xpart = tmp + (size_t)M_ROWS * D_MODEL;       // XSK*2048*128

    float* Hbuf = tmp;
    float* Pbuf = tmp + (size_t)BATCH * NC * D_STATE * D_INNER;
    float* opart = xpart;   // out_proj partials alias xpart

    unsigned short* xb     = (unsigned short*)(xpart + (size_t)XSK * M_ROWS * XPAD);
    unsigned short* yb     = xb + (size_t)M_ROWS * D_MODEL;
    unsigned short* xzb    = yb + (size_t)M_ROWS * D_INNER;
    unsigned short* xcb    = xzb + (size_t)M_ROWS * 2 * D_INNER;
    unsigned short* dtb    = xcb + (size_t)M_ROWS * D_INNER;
    unsigned short* xdbl_b = dtb + (size_t)M_ROWS * D_INNER;
    unsigned short* wb_in  = xdbl_b + (size_t)M_ROWS * XPAD;
    unsigned short* wb_out = wb_in + (size_t)NLAYERS * 2 * D_INNER * D_MODEL;
    unsigned short* wb_fc  = wb_out + (size_t)NLAYERS * D_MODEL * D_INNER;
    unsigned short* wb_x   = wb_fc + (size_t)VOCAB * D_MODEL;
    unsigned short* wb_dt  = wb_x + (size_t)NLAYERS * XPAD * D_INNER;

    // ---- all weight casts in ONE launch ----
    cast_all<<<(CAST_TOT + 255) / 256, 256, 0, stream>>>(
        in_proj, out_proj, fc_w, dt_w, x_proj, wb_in, wb_out, wb_fc, wb_dt, wb_x);

    // ---- embedding (fp32 + bf16) ----
    gather_kernel<<<M_ROWS, 256, 0, stream>>>(ids, embed, x, xb);

    for (int i = 0; i < NLAYERS; ++i) {
        const unsigned short* W_in_b  = wb_in + (size_t)i * 2 * D_INNER * D_MODEL;
        const unsigned short* W_out_b = wb_out + (size_t)i * D_MODEL * D_INNER;
        const unsigned short* W_x_b   = wb_x + (size_t)i * XPAD * D_INNER;
        const unsigned short* W_dt_b  = wb_dt + (size_t)i * D_INNER * DT_RANK;
        const float* cw    = conv_w + (size_t)i * D_INNER * 4;
        const float* cb    = conv_b + (size_t)i * D_INNER;
        const float* b_dt  = dt_b + (size_t)i * D_INNER;
        const float* Al    = A_log + (size_t)i * D_INNER * D_STATE;
        const float* Dl    = Dp + (size_t)i * D_INNER;
        const float* g     = ln_g + (size_t)i * D_MODEL;
        const float* bb    = ln_b + (size_t)i * D_MODEL;

        // xz(bf16) = x @ in_proj^T   (2048 x 4096, K=1024)   grid 16x32
        gemm_bf16_nt<1><<<dim3(M_ROWS / 128, 2 * D_INNER / 128), 256, 0, stream>>>(
            xb, D_MODEL, W_in_b, D_MODEL, xzb, 2 * D_INNER, D_MODEL, nullptr);

        // xc(bf16) = silu(conv(xz[:, :2048]) + cb)
        conv_silu_kernel<<<(M_ROWS * D_INNER) / 256, 256, 0, stream>>>(xzb, cw, cb, xcb);

        // x_dbl partials: (2048 x 128, K=2048 split XSK x 128)  grid 16x1x16
        gemm_bf16_nt<0><<<dim3(M_ROWS / 128, 1, XSK), 256, 0, stream>>>(
            xcb, D_INNER, W_x_b, D_INNER, xpart, XPAD, D_INNER / XSK, nullptr);
        reduce_xdbl<<<(M_ROWS * XPAD / 4) / 256, 256, 0, stream>>>(xpart, xdbl, xdbl_b);

        // dt(bf16) = softplus(x_dbl[:, :64] @ dt_w^T + b_dt)  (2048x2048, K=64) grid 16x16
        gemm_bf16_nt<3><<<dim3(M_ROWS / 128, D_INNER / 128), 256, 0, stream>>>(
            xdbl_b, XPAD, W_dt_b, DT_RANK, dtb, D_INNER, DT_RANK, b_dt);

        // chunk-parallel scan -> yb (bf16)
        scan_partial<<<BATCH * NC * (D_INNER / 256), 256, 0, stream>>>(
            dtb, xdbl, xcb, Al, Hbuf, Pbuf);
        scan_combine<<<(BATCH * D_STATE * D_INNER) / 256, 256, 0, stream>>>(Hbuf, Pbuf);
        scan_final<<<BATCH * NC * (D_INNER / 256), 256, 0, stream>>>(
            dtb, xdbl, xcb, xzb, Al, Dl, Pbuf, yb);

        // out_proj partials: (2048 x 1024, K=2048 split 2 x 1024)  grid 16x8x2
        gemm_bf16_nt<0><<<dim3(M_ROWS / 128, D_MODEL / 128, OSK), 256, 0, stream>>>(
            yb, D_INNER, W_out_b, D_INNER, opart, D_MODEL, D_INNER / OSK, nullptr);

        // x = LN(opart0 + opart1 + x)  (fp32 + bf16)
        ln_kernel<2><<<M_ROWS, 256, 0, stream>>>(
            opart, opart + (size_t)M_ROWS * D_MODEL, x, x, xb, g, bb);
    }

    // final LN -> tmp + xb
    ln_kernel<0><<<M_ROWS, 256, 0, stream>>>(nullptr, nullptr, x, tmp, xb, fn_g, fn_b);

    // logits = xf @ fc_w^T + fc_b   (2048 x 32000, K=1024)  8-phase 256² grid 8x125
    gemm_bf16_8ph<<<dim3(M_ROWS / 256, VOCAB / 256), 512, 0, stream>>>(
        xb, D_MODEL, wb_fc, D_MODEL, logits, VOCAB, D_MODEL, fc_b);
}

// Round 16
// 882.192 us; speedup vs baseline: 1.0784x; 1.0784x over previous
//
#include <hip/hip_runtime.h>
#include <cstddef>
#include <cstdint>

#define D_MODEL 1024
#define D_INNER 2048
#define DT_RANK 64
#define D_STATE 8
#define NLAYERS 4
#define BATCH 2
#define SEQ 1024
#define M_ROWS (BATCH*SEQ)   /* 2048 */
#define VOCAB 32000
#define XPAD 128             /* x_proj N padded 80 -> 128 */
#define NC 32                /* scan chunks */
#define LC 32                /* chunk length (NC*LC == SEQ) */
#define XSK 16               /* x_proj split-K factor */
#define OSK 2                /* out_proj split-K factor */

typedef __attribute__((ext_vector_type(8))) short short8;
typedef __attribute__((ext_vector_type(4))) float f32x4;

#define GPTR(p) (const __attribute__((address_space(1))) void*)(p)
#define LPTR(p) (__attribute__((address_space(3))) void*)(p)

__device__ __forceinline__ float sigmoidf_(float x) { return 1.f / (1.f + __expf(-x)); }

__device__ __forceinline__ unsigned short f2bf(float f) {
    unsigned u = __float_as_uint(f);
    u += 0x7fffu + ((u >> 16) & 1u);         // round-to-nearest-even
    return (unsigned short)(u >> 16);
}
__device__ __forceinline__ float bf2f(unsigned short u) {
    return __uint_as_float((unsigned)u << 16);
}

// ---------------------------------------------------------------------------
// Merged weight cast: all 5 regions in ONE launch (region-dispatch on index).
// ---------------------------------------------------------------------------
#define N4_IN  (NLAYERS * 2 * D_INNER * D_MODEL / 4)
#define N4_OUT (NLAYERS * D_MODEL * D_INNER / 4)
#define N4_FC  (VOCAB * D_MODEL / 4)
#define N4_DT  (NLAYERS * D_INNER * DT_RANK / 4)
#define N4_XP  (NLAYERS * XPAD * D_INNER / 4)
#define CAST_O1 (N4_IN)
#define CAST_O2 (CAST_O1 + N4_OUT)
#define CAST_O3 (CAST_O2 + N4_FC)
#define CAST_O4 (CAST_O3 + N4_DT)
#define CAST_TOT (CAST_O4 + N4_XP)

__device__ __forceinline__ void cast4(const float* __restrict__ in,
                                      unsigned short* __restrict__ out, int j)
{
    float4 v = ((const float4*)in)[j];
    ushort4 o;
    o.x = f2bf(v.x); o.y = f2bf(v.y); o.z = f2bf(v.z); o.w = f2bf(v.w);
    ((ushort4*)out)[j] = o;
}

__global__ __launch_bounds__(256) void cast_all(const float* __restrict__ in_proj,
                                                const float* __restrict__ out_proj,
                                                const float* __restrict__ fc_w,
                                                const float* __restrict__ dt_w,
                                                const float* __restrict__ x_proj,
                                                unsigned short* __restrict__ wb_in,
                                                unsigned short* __restrict__ wb_out,
                                                unsigned short* __restrict__ wb_fc,
                                                unsigned short* __restrict__ wb_dt,
                                                unsigned short* __restrict__ wb_x)
{
    int i = blockIdx.x * 256 + threadIdx.x;
    if (i < CAST_O1) {
        cast4(in_proj, wb_in, i);
    } else if (i < CAST_O2) {
        cast4(out_proj, wb_out, i - CAST_O1);
    } else if (i < CAST_O3) {
        cast4(fc_w, wb_fc, i - CAST_O2);
    } else if (i < CAST_O4) {
        cast4(dt_w, wb_dt, i - CAST_O3);
    } else if (i < CAST_TOT) {
        int i2 = i - CAST_O4;
        int col4 = i2 & (D_INNER / 4 - 1);
        int row = (i2 >> 9) & (XPAD - 1);
        int layer = i2 >> 16;
        ushort4 o = {0, 0, 0, 0};
        if (row < 80) {
            float4 v = ((const float4*)(x_proj + ((size_t)layer * 80 + row) * D_INNER))[col4];
            o.x = f2bf(v.x); o.y = f2bf(v.y); o.z = f2bf(v.z); o.w = f2bf(v.w);
        }
        ((ushort4*)wb_x)[i2] = o;
    }
}

// ---------------------------------------------------------------------------
// Embedding gather -> x (fp32) and xb (bf16)
// ---------------------------------------------------------------------------
__global__ __launch_bounds__(256) void gather_kernel(const int* __restrict__ ids,
                                                     const float* __restrict__ embed,
                                                     float* __restrict__ x,
                                                     unsigned short* __restrict__ xb)
{
    int m = blockIdx.x;
    int t = threadIdx.x;
    int id = ids[m];
    float4 v = ((const float4*)(embed + (size_t)id * D_MODEL))[t];
    ((float4*)(x + (size_t)m * D_MODEL))[t] = v;
    ushort4 o;
    o.x = f2bf(v.x); o.y = f2bf(v.y); o.z = f2bf(v.z); o.w = f2bf(v.w);
    ((ushort4*)(xb + (size_t)m * D_MODEL))[t] = o;
}

// ---------------------------------------------------------------------------
// bf16 MFMA GEMM  C[M,N] = A[M,K] * B[N,K]^T
// 128x128 tile, BK=32, 4 waves. Double-buffered LDS, counted-vmcnt pipeline.
// EPI: 0 fp32 (+splitK z-offset) | 1 bf16 | 2 fp32 +bias | 3 bf16 softplus(v+bias)
// ---------------------------------------------------------------------------
template<int EPI>
__global__ __launch_bounds__(256) void gemm_bf16_nt(const unsigned short* __restrict__ A, int lda,
                                                    const unsigned short* __restrict__ B, int ldb,
                                                    void* __restrict__ Cv, int ldc,
                                                    int K, const float* __restrict__ bias)
{
    __shared__ unsigned short As[2][128 * 32];
    __shared__ unsigned short Bs[2][128 * 32];
    const int tid = threadIdx.x;

    const int gm = gridDim.x;
    const int bid = blockIdx.y * gm + blockIdx.x;
    const int q = (gm * gridDim.y) >> 3;           // nwg % 8 == 0 guaranteed
    const int swz = (bid & 7) * q + (bid >> 3);
    const int bm = (swz % gm) * 128, bn = (swz / gm) * 128;

    const int wid = tid >> 6, lane = tid & 63;
    const int wm = (wid >> 1) * 64, wn = (wid & 1) * 64;
    const int lrow = lane & 15, lkg = lane >> 4;

    const int srow = tid >> 2;                               // 0..63
    const int ksrc = ((tid & 3) ^ ((srow >> 1) & 3)) * 8;    // elems, const/thread
    const size_t kz = (size_t)blockIdx.z * K;
    const unsigned short* Ag = A + (size_t)(bm + srow) * lda + kz + ksrc;
    const unsigned short* Bg = B + (size_t)(bn + srow) * ldb + kz + ksrc;
    const size_t r64a = (size_t)64 * lda;
    const size_t r64b = (size_t)64 * ldb;

#define STAGE(buf, koff)                                                                              \
    do {                                                                                              \
        __builtin_amdgcn_global_load_lds(GPTR(Ag + (koff)),        LPTR(&As[buf][tid * 8]), 16, 0, 0);\
        __builtin_amdgcn_global_load_lds(GPTR(Ag + r64a + (koff)), LPTR(&As[buf][2048 + tid * 8]), 16, 0, 0);\
        __builtin_amdgcn_global_load_lds(GPTR(Bg + (koff)),        LPTR(&Bs[buf][tid * 8]), 16, 0, 0);\
        __builtin_amdgcn_global_load_lds(GPTR(Bg + r64b + (koff)), LPTR(&Bs[buf][2048 + tid * 8]), 16, 0, 0);\
    } while (0)

    f32x4 acc[4][4];
    #pragma unroll
    for (int i = 0; i < 4; ++i)
        #pragma unroll
        for (int j = 0; j < 4; ++j)
            acc[i][j] = f32x4{0.f, 0.f, 0.f, 0.f};

    STAGE(0, 0);                      // prologue

    int cur = 0;
    for (int k0 = 0; k0 < K; k0 += 32) {
        if (k0 + 32 < K) {
            STAGE(cur ^ 1, k0 + 32);                             // next tile in flight
            asm volatile("s_waitcnt vmcnt(4)" ::: "memory");     // cur's 4 landed
        } else {
            asm volatile("s_waitcnt vmcnt(0)" ::: "memory");     // final drain
        }
        __builtin_amdgcn_s_barrier();          // publish cur to all waves
        __builtin_amdgcn_sched_barrier(0);     // pin: no hoisting above the wait

        short8 af[4], bf[4];
        #pragma unroll
        for (int i = 0; i < 4; ++i) {
            int ra = wm + 16 * i + lrow;
            int pa = lkg ^ ((ra >> 1) & 3);
            af[i] = *(const short8*)(&As[cur][ra * 32 + pa * 8]);
            int rb = wn + 16 * i + lrow;
            int pb = lkg ^ ((rb >> 1) & 3);
            bf[i] = *(const short8*)(&Bs[cur][rb * 32 + pb * 8]);
        }
        __builtin_amdgcn_s_setprio(1);
        #pragma unroll
        for (int i = 0; i < 4; ++i)
            #pragma unroll
            for (int j = 0; j < 4; ++j)
                acc[i][j] = __builtin_amdgcn_mfma_f32_16x16x32_bf16(af[i], bf[j], acc[i][j], 0, 0, 0);
        __builtin_amdgcn_s_setprio(0);

        __builtin_amdgcn_s_barrier();          // all reads of cur done before overwrite
        cur ^= 1;
    }
#undef STAGE

    const int crow = bm + wm + lkg * 4;
    const int ccol = bn + wn + lrow;
    #pragma unroll
    for (int i = 0; i < 4; ++i) {
        #pragma unroll
        for (int j = 0; j < 4; ++j) {
            float bv = (EPI == 2 || EPI == 3) ? bias[ccol + 16 * j] : 0.f;
            #pragma unroll
            for (int r = 0; r < 4; ++r) {
                float v = acc[i][j][r] + bv;
                size_t off = (size_t)(crow + 16 * i + r) * ldc + ccol + 16 * j;
                if (EPI == 0) {
                    ((float*)Cv)[(size_t)blockIdx.z * M_ROWS * ldc + off] = v;
                } else if (EPI == 2) {
                    ((float*)Cv)[off] = v;
                } else {
                    if (EPI == 3) v = (v > 20.f) ? v : log1pf(__expf(v));
                    ((unsigned short*)Cv)[off] = f2bf(v);
                }
            }
        }
    }
}

// ---------------------------------------------------------------------------
// 8-phase 256x256 GEMM (m201 template, uniform fine interleave).
// 512 thr = 8 waves (2M x 4N); 2 K-tiles (BK=64)/iter; LDS 128 KiB.
// EXACTLY ONE half-tile (2 gloads) staged per phase (m196 lever):
//   P1:A(T1)h1  P2:B(T0+2)h0  P3:B(T0+2)h1  P4:A(T0+2)h0
//   P5:A(T0+2)h1  P6:B(T1+2)h0  P7:B(T1+2)h1  P8:A(T1+2)h0
// vmcnt(6) ONLY at P4 and P8 (3 half-tiles in flight).
// Buffer safety: every stage >=1 end-barrier after its half's last read
// (b0 saved in b0s so Bs h0 frees at P1/P5). T2 swizzle p = u ^ (row&7);
// inverse-swizzled global source (rule #21).
// ---------------------------------------------------------------------------
__device__ __forceinline__ void rd_a8(const unsigned short* S, int base, int lrow, int lkg, short8 a[4][2]) {
    #pragma unroll
    for (int i = 0; i < 4; ++i)
        #pragma unroll
        for (int kk = 0; kk < 2; ++kk) {
            int row = base + i * 16 + lrow;
            int p = (kk * 4 + lkg) ^ (lrow & 7);
            a[i][kk] = *(const short8*)(S + row * 64 + p * 8);
        }
}
__device__ __forceinline__ void rd_b4(const unsigned short* S, int base, int lrow, int lkg, short8 b[2][2]) {
    #pragma unroll
    for (int j = 0; j < 2; ++j)
        #pragma unroll
        for (int kk = 0; kk < 2; ++kk) {
            int row = base + j * 16 + lrow;
            int p = (kk * 4 + lkg) ^ (lrow & 7);
            b[j][kk] = *(const short8*)(S + row * 64 + p * 8);
        }
}

__global__ __launch_bounds__(512) void gemm_bf16_8ph(const unsigned short* __restrict__ A, int lda,
                                                     const unsigned short* __restrict__ B, int ldb,
                                                     float* __restrict__ C, int ldc,
                                                     int K, const float* __restrict__ bias)
{
    __shared__ unsigned short As[2][256 * 64];
    __shared__ unsigned short Bs[2][256 * 64];
    const int tid = threadIdx.x;

    const int gm = gridDim.x;
    const int bid = blockIdx.y * gm + blockIdx.x;
    const int q = (gm * gridDim.y) >> 3;
    const int swz = (bid & 7) * q + (bid >> 3);
    const int bm = (swz % gm) * 256, bn = (swz / gm) * 256;

    const int wid = tid >> 6, lane = tid & 63;
    const int wr = wid >> 2, wc = wid & 3;
    const int arow0 = wr * 128;                 // wave's A half
    const int b0r = wc * 32, b1r = 128 + wc * 32;
    const int lrow = lane & 15, lkg = lane >> 4;

    const int sg = tid >> 3, su = tid & 7;      // staging row-in-64 / unit
    const int ksrc = (su ^ (sg & 7)) * 8;       // inverse-swizzled global src
    const unsigned short* Ag = A + (size_t)(bm + sg) * lda + ksrc;
    const unsigned short* Bg = B + (size_t)(bn + sg) * ldb + ksrc;

#define STG_A_H(buf, kt, h) do {                                                                   \
    __builtin_amdgcn_global_load_lds(GPTR(Ag + (size_t)(kt) * 64 + (size_t)((h) * 128) * lda),     \
                                     LPTR(&As[buf][(h) * 8192 + tid * 8]), 16, 0, 0);              \
    __builtin_amdgcn_global_load_lds(GPTR(Ag + (size_t)(kt) * 64 + (size_t)((h) * 128 + 64) * lda),\
                                     LPTR(&As[buf][(h) * 8192 + 4096 + tid * 8]), 16, 0, 0);       \
} while (0)
#define STG_B_H(buf, kt, h) do {                                                                   \
    __builtin_amdgcn_global_load_lds(GPTR(Bg + (size_t)(kt) * 64 + (size_t)((h) * 128) * ldb),     \
                                     LPTR(&Bs[buf][(h) * 8192 + tid * 8]), 16, 0, 0);              \
    __builtin_amdgcn_global_load_lds(GPTR(Bg + (size_t)(kt) * 64 + (size_t)((h) * 128 + 64) * ldb),\
                                     LPTR(&Bs[buf][(h) * 8192 + 4096 + tid * 8]), 16, 0, 0);       \
} while (0)
#define WAITN(n) asm volatile("s_waitcnt vmcnt(" #n ")" ::: "memory")
#define PBAR() __builtin_amdgcn_s_barrier()
#define SBAR() __builtin_amdgcn_sched_barrier(0)
#define MFMA_Q(QA, BH, BARR) do {                                                                  \
    __builtin_amdgcn_s_setprio(1);                                                                 \
    _Pragma("unroll") for (int i = 0; i < 4; ++i)                                                  \
    _Pragma("unroll") for (int j = 0; j < 2; ++j)                                                  \
    _Pragma("unroll") for (int kk = 0; kk < 2; ++kk)                                               \
        acc[(QA) * 4 + i][(BH) * 2 + j] =                                                          \
            __builtin_amdgcn_mfma_f32_16x16x32_bf16(a[i][kk], BARR[j][kk],                         \
                                                    acc[(QA) * 4 + i][(BH) * 2 + j], 0, 0, 0);     \
    __builtin_amdgcn_s_setprio(0);                                                                 \
} while (0)

    f32x4 acc[8][4];
    #pragma unroll
    for (int i = 0; i < 8; ++i)
        #pragma unroll
        for (int j = 0; j < 4; ++j)
            acc[i][j] = f32x4{0.f, 0.f, 0.f, 0.f};

    short8 a[4][2], b[2][2], b0s[2][2];
    const int NT = K >> 6;        // 16 K-tiles
    const int NI = NT >> 1;       // 8 iterations

    // prologue: T0 fully (4 half-tiles), then A(T1)h0, B(T1)h0, B(T1)h1.
    // WAITN(6): 14 loads issued, wait until <=6 outstanding -> first 8 (=T0) landed.
    STG_A_H(0, 0, 0); STG_A_H(0, 0, 1); STG_B_H(0, 0, 0); STG_B_H(0, 0, 1);
    STG_A_H(1, 1, 0); STG_B_H(1, 1, 0); STG_B_H(1, 1, 1);
    WAITN(6);
    PBAR();

    for (int it = 0; it < NI; ++it) {
        const int T1 = 2 * it + 1;
        const int T0n = 2 * it + 2, T1n = 2 * it + 3;   // prefetch targets
        const bool more = (it + 1 < NI);

        // P1: stage A(T1)h1; read a0(T0), b0(T0)->b0s; Q(0,0)
        STG_A_H(1, T1, 1);
        rd_a8(As[0], arow0, lrow, lkg, a);
        rd_b4(Bs[0], b0r, lrow, lkg, b0s);
        PBAR(); SBAR();
        MFMA_Q(0, 0, b0s);
        PBAR();
        // P2: stage B(T0+2)h0 (Bs[0]h0 free since P1 via b0s); read b1(T0)=h1; Q(0,1)
        if (more) STG_B_H(0, T0n, 0);
        rd_b4(Bs[0], b1r, lrow, lkg, b);
        PBAR(); SBAR();
        MFMA_Q(0, 1, b);
        PBAR();
        // P3: stage B(T0+2)h1 (h1 last read P2); read a1(T0); Q(1,1)
        if (more) STG_B_H(0, T0n, 1);
        rd_a8(As[0], arow0 + 64, lrow, lkg, a);
        PBAR(); SBAR();
        MFMA_Q(1, 1, b);
        PBAR();
        // P4: stage A(T0+2)h0 (As[0] last read P3); WAIT(6): forces slot-P1
        //     (A(T1)h1) landed -> P5 reads safe. Q(1,0) from regs.
        if (more) { STG_A_H(0, T0n, 0); WAITN(6); } else { WAITN(0); }
        PBAR(); SBAR();
        MFMA_Q(1, 0, b0s);
        PBAR();
        // P5: stage A(T0+2)h1; read a0(T1), b0(T1)->b0s; Q(0,0)
        if (more) STG_A_H(0, T0n, 1);
        rd_a8(As[1], arow0, lrow, lkg, a);
        rd_b4(Bs[1], b0r, lrow, lkg, b0s);
        PBAR(); SBAR();
        MFMA_Q(0, 0, b0s);
        PBAR();
        // P6: stage B(T1+2)h0 (Bs[1]h0 free since P5 via b0s); read b1(T1); Q(0,1)
        if (more) STG_B_H(1, T1n, 0);
        rd_b4(Bs[1], b1r, lrow, lkg, b);
        PBAR(); SBAR();
        MFMA_Q(0, 1, b);
        PBAR();
        // P7: stage B(T1+2)h1 (h1 last read P6); read a1(T1); Q(1,1)
        if (more) STG_B_H(1, T1n, 1);
        rd_a8(As[1], arow0 + 64, lrow, lkg, a);
        PBAR(); SBAR();
        MFMA_Q(1, 1, b);
        PBAR();
        // P8: stage A(T1+2)h0 (As[1] last read P7); WAIT(6): forces slots
        //     P2..P5 landed -> next-iter P1-P3 reads safe. Q(1,0) from regs.
        if (more) { STG_A_H(1, T1n, 0); WAITN(6); } else { WAITN(0); }
        PBAR(); SBAR();
        MFMA_Q(1, 0, b0s);
        PBAR();
    }
#undef STG_A_H
#undef STG_B_H
#undef WAITN
#undef PBAR
#undef SBAR
#undef MFMA_Q

    // C write: row = bm + arow0 + i*16 + lkg*4 + r;
    // col(j) = bn + (j>>1)*128 + wc*32 + (j&1)*16 + lrow
    const int crow = bm + arow0 + lkg * 4;
    #pragma unroll
    for (int i = 0; i < 8; ++i) {
        #pragma unroll
        for (int j = 0; j < 4; ++j) {
            int ccol = bn + (j >> 1) * 128 + wc * 32 + (j & 1) * 16 + lrow;
            float bv = bias[ccol];
            float* Cp = C + (size_t)(crow + 16 * i) * ldc + ccol;
            #pragma unroll
            for (int r = 0; r < 4; ++r)
                Cp[(size_t)r * ldc] = acc[i][j][r] + bv;
        }
    }
}

// ---------------------------------------------------------------------------
// Reduce XSK split-K partials -> xdbl (fp32) + xdbl_b (bf16)
// ---------------------------------------------------------------------------
__global__ __launch_bounds__(256) void reduce_xdbl(const float* __restrict__ part,
                                                   float* __restrict__ xdbl,
                                                   unsigned short* __restrict__ xdbl_b)
{
    int i = blockIdx.x * 256 + threadIdx.x;     // over 2048*128/4 = 65536
    float4 s = ((const float4*)part)[i];
    #pragma unroll
    for (int z = 1; z < XSK; ++z) {
        float4 v = ((const float4*)part)[(size_t)z * (M_ROWS * XPAD / 4) + i];
        s.x += v.x; s.y += v.y; s.z += v.z; s.w += v.w;
    }
    ((float4*)xdbl)[i] = s;
    ushort4 o;
    o.x = f2bf(s.x); o.y = f2bf(s.y); o.z = f2bf(s.z); o.w = f2bf(s.w);
    ((ushort4*)xdbl_b)[i] = o;
}

// ---------------------------------------------------------------------------
// Causal depthwise conv1d (k=4) + bias + SiLU; bf16 in (xzb) -> bf16 out (xcb)
// ---------------------------------------------------------------------------
__global__ __launch_bounds__(256) void conv_silu_kernel(const unsigned short* __restrict__ xzb,
                                                        const float* __restrict__ cw,
                                                        const float* __restrict__ cb,
                                                        unsigned short* __restrict__ xcb)
{
    int idx = blockIdx.x * 256 + threadIdx.x;
    int d = idx & (D_INNER - 1);
    int m = idx >> 11;
    int l = m & (SEQ - 1);
    int b = m >> 10;
    float w0 = cw[d * 4 + 0], w1 = cw[d * 4 + 1], w2 = cw[d * 4 + 2], w3 = cw[d * 4 + 3];
    float s = cb[d];
    const unsigned short* base = xzb + ((size_t)b * SEQ) * (2 * D_INNER) + d;
    if (l - 3 >= 0) s += bf2f(base[(size_t)(l - 3) * (2 * D_INNER)]) * w0;
    if (l - 2 >= 0) s += bf2f(base[(size_t)(l - 2) * (2 * D_INNER)]) * w1;
    if (l - 1 >= 0) s += bf2f(base[(size_t)(l - 1) * (2 * D_INNER)]) * w2;
    s += bf2f(base[(size_t)l * (2 * D_INNER)]) * w3;
    float v = s * sigmoidf_(s);
    xcb[(size_t)m * D_INNER + d] = f2bf(v);
}

// ---------------------------------------------------------------------------
// Chunk-parallel selective scan (linear recurrence decomposition).
// 1 d per thread (latency-bound: maximize wave count).
// ---------------------------------------------------------------------------
__global__ __launch_bounds__(256) void scan_partial(const unsigned short* __restrict__ dtb,
                                                    const float* __restrict__ xdbl,
                                                    const unsigned short* __restrict__ xcb,
                                                    const float* __restrict__ A_log,
                                                    float* __restrict__ H,
                                                    float* __restrict__ P)
{
    const int tid = threadIdx.x;
    const int b = blockIdx.x & 1;
    const int c = (blockIdx.x >> 1) & (NC - 1);
    const int d = ((blockIdx.x >> 6) << 8) + tid;

    __shared__ float Bsm[LC][8];
    {
        int r = tid >> 3, n = tid & 7;
        Bsm[r][n] = xdbl[(size_t)(b * SEQ + c * LC + r) * XPAD + DT_RANK + n];
    }
    __syncthreads();

    float An[8];
    #pragma unroll
    for (int n = 0; n < 8; ++n) An[n] = -__expf(A_log[d * 8 + n]);
    float h[8] = {0.f,0.f,0.f,0.f,0.f,0.f,0.f,0.f};
    float p[8] = {1.f,1.f,1.f,1.f,1.f,1.f,1.f,1.f};

    const unsigned short* dtp = dtb + (size_t)(b * SEQ + c * LC) * D_INNER + d;
    const unsigned short* xcp = xcb + (size_t)(b * SEQ + c * LC) * D_INNER + d;
    for (int l = 0; l < LC; ++l) {
        float dtv = bf2f(dtp[(size_t)l * D_INNER]);
        float ux  = dtv * bf2f(xcp[(size_t)l * D_INNER]);
        #pragma unroll
        for (int n = 0; n < 8; ++n) {
            float dA = __expf(dtv * An[n]);
            h[n] = dA * h[n] + Bsm[l][n] * ux;
            p[n] *= dA;
        }
    }
    size_t base = (size_t)((b * NC + c) * 8) * D_INNER + d;
    #pragma unroll
    for (int n = 0; n < 8; ++n) {
        H[base + (size_t)n * D_INNER] = h[n];
        P[base + (size_t)n * D_INNER] = p[n];
    }
}

__global__ __launch_bounds__(256) void scan_combine(const float* __restrict__ H,
                                                    float* __restrict__ P /* -> h0 */)
{
    int idx = blockIdx.x * 256 + threadIdx.x;   // 32768 = 2*8*2048
    int d = idx & (D_INNER - 1);
    int n = (idx >> 11) & 7;
    int b = idx >> 14;
    float hp = 0.f;
    for (int c = 0; c < NC; ++c) {
        size_t base = (size_t)((b * NC + c) * 8 + n) * D_INNER + d;
        float Pv = P[base], Hv = H[base];
        P[base] = hp;
        hp = Pv * hp + Hv;
    }
}

__global__ __launch_bounds__(256) void scan_final(const unsigned short* __restrict__ dtb,
                                                  const float* __restrict__ xdbl,
                                                  const unsigned short* __restrict__ xcb,
                                                  const unsigned short* __restrict__ xzb,
                                                  const float* __restrict__ A_log,
                                                  const float* __restrict__ Dp,
                                                  const float* __restrict__ h0,
                                                  unsigned short* __restrict__ yb)
{
    const int tid = threadIdx.x;
    const int b = blockIdx.x & 1;
    const int c = (blockIdx.x >> 1) & (NC - 1);
    const int d = ((blockIdx.x >> 6) << 8) + tid;

    __shared__ float Bsm[LC][8];
    __shared__ float Csm[LC][8];
    {
        int r = tid >> 3, n = tid & 7;
        size_t xrow = (size_t)(b * SEQ + c * LC + r) * XPAD;
        Bsm[r][n] = xdbl[xrow + DT_RANK + n];
        Csm[r][n] = xdbl[xrow + DT_RANK + 8 + n];
    }
    __syncthreads();

    float An[8], h[8];
    size_t base = (size_t)((b * NC + c) * 8) * D_INNER + d;
    #pragma unroll
    for (int n = 0; n < 8; ++n) {
        An[n] = -__expf(A_log[d * 8 + n]);
        h[n] = h0[base + (size_t)n * D_INNER];
    }
    const float Dv = Dp[d];

    const unsigned short* dtp = dtb + (size_t)(b * SEQ + c * LC) * D_INNER + d;
    const unsigned short* xcp = xcb + (size_t)(b * SEQ + c * LC) * D_INNER + d;
    const unsigned short* zp  = xzb + (size_t)(b * SEQ + c * LC) * (2 * D_INNER) + D_INNER + d;
    unsigned short* ybp = yb + (size_t)(b * SEQ + c * LC) * D_INNER + d;

    for (int l = 0; l < LC; ++l) {
        float dtv = bf2f(dtp[(size_t)l * D_INNER]);
        float xcv = bf2f(xcp[(size_t)l * D_INNER]);
        float zv  = bf2f(zp[(size_t)l * (2 * D_INNER)]);
        float ux = dtv * xcv;
        float acc = 0.f;
        #pragma unroll
        for (int n = 0; n < 8; ++n) {
            float dA = __expf(dtv * An[n]);
            h[n] = dA * h[n] + Bsm[l][n] * ux;
            acc += h[n] * Csm[l][n];
        }
        float yv = (acc + xcv * Dv) * (zv * sigmoidf_(zv));
        ybp[(size_t)l * D_INNER] = f2bf(yv);
    }
}

// ---------------------------------------------------------------------------
// LayerNorm (1024). NEXTRA extras summed with xin. Emits fp32 + bf16.
// ---------------------------------------------------------------------------
template<int NEXTRA>
__global__ __launch_bounds__(256) void ln_kernel(const float* __restrict__ e0,
                                                 const float* __restrict__ e1,
                                                 const float* __restrict__ xin,
                                                 float* __restrict__ xout,
                                                 unsigned short* __restrict__ xbout,
                                                 const float* __restrict__ g,
                                                 const float* __restrict__ bb)
{
    int m = blockIdx.x;
    int t = threadIdx.x;
    float4 v = ((const float4*)(xin + (size_t)m * D_MODEL))[t];
    if (NEXTRA >= 1) {
        float4 e = ((const float4*)(e0 + (size_t)m * D_MODEL))[t];
        v.x += e.x; v.y += e.y; v.z += e.z; v.w += e.w;
    }
    if (NEXTRA >= 2) {
        float4 e = ((const float4*)(e1 + (size_t)m * D_MODEL))[t];
        v.x += e.x; v.y += e.y; v.z += e.z; v.w += e.w;
    }
    float s  = v.x + v.y + v.z + v.w;
    float s2 = v.x * v.x + v.y * v.y + v.z * v.z + v.w * v.w;
    for (int off = 32; off; off >>= 1) {
        s  += __shfl_down(s, off);
        s2 += __shfl_down(s2, off);
    }
    __shared__ float red[8];
    int wid = t >> 6, lane = t & 63;
    if (lane == 0) { red[wid] = s; red[wid + 4] = s2; }
    __syncthreads();
    if (t == 0) {
        float a  = red[0] + red[1] + red[2] + red[3];
        float b2 = red[4] + red[5] + red[6] + red[7];
        float mu = a * (1.f / D_MODEL);
        red[0] = mu;
        red[4] = b2 * (1.f / D_MODEL) - mu * mu;
    }
    __syncthreads();
    float mu = red[0];
    float rs = rsqrtf(red[4] + 1e-5f);
    float4 gg = ((const float4*)g)[t];
    float4 bv = ((const float4*)bb)[t];
    float4 o;
    o.x = (v.x - mu) * rs * gg.x + bv.x;
    o.y = (v.y - mu) * rs * gg.y + bv.y;
    o.z = (v.z - mu) * rs * gg.z + bv.z;
    o.w = (v.w - mu) * rs * gg.w + bv.w;
    ((float4*)(xout + (size_t)m * D_MODEL))[t] = o;
    ushort4 ob;
    ob.x = f2bf(o.x); ob.y = f2bf(o.y); ob.z = f2bf(o.z); ob.w = f2bf(o.w);
    ((ushort4*)(xbout + (size_t)m * D_MODEL))[t] = ob;
}

// ---------------------------------------------------------------------------
extern "C" void kernel_launch(void* const* d_in, const int* in_sizes, int n_in,
                              void* d_out, int out_size, void* d_ws, size_t ws_size,
                              hipStream_t stream)
{
    const int*   ids      = (const int*)d_in[0];
    const float* embed    = (const float*)d_in[1];
    const float* in_proj  = (const float*)d_in[2];
    const float* conv_w   = (const float*)d_in[3];
    const float* conv_b   = (const float*)d_in[4];
    const float* x_proj   = (const float*)d_in[5];
    const float* dt_w     = (const float*)d_in[6];
    const float* dt_b     = (const float*)d_in[7];
    const float* A_log    = (const float*)d_in[8];
    const float* Dp       = (const float*)d_in[9];
    const float* out_proj = (const float*)d_in[10];
    const float* ln_g     = (const float*)d_in[11];
    const float* ln_b     = (const float*)d_in[12];
    const float* fn_g     = (const float*)d_in[13];
    const float* fn_b     = (const float*)d_in[14];
    const float* fc_w     = (const float*)d_in[15];
    const float* fc_b     = (const float*)d_in[16];
    float* logits = (float*)d_out;

    // ---- workspace layout (fp32 first, then bf16) ----
    float* ws = (float*)d_ws;
    float* x     = ws;                                   // 2048*1024
    float* xdbl  = x + (size_t)M_ROWS * D_MODEL;         // 2048*128
    float* tmp   = xdbl + (size_t)M_ROWS * XPAD;         // 2048*1024 (H/P alias)
    float* xpart = tmp + (size_t)M_ROWS * D_MODEL;       // XSK*2048*128

    float* Hbuf = tmp;
    float* Pbuf = tmp + (size_t)BATCH * NC * D_STATE * D_INNER;
    float* opart = xpart;   // out_proj partials alias xpart

    unsigned short* xb     = (unsigned short*)(xpart + (size_t)XSK * M_ROWS * XPAD);
    unsigned short* yb     = xb + (size_t)M_ROWS * D_MODEL;
    unsigned short* xzb    = yb + (size_t)M_ROWS * D_INNER;
    unsigned short* xcb    = xzb + (size_t)M_ROWS * 2 * D_INNER;
    unsigned short* dtb    = xcb + (size_t)M_ROWS * D_INNER;
    unsigned short* xdbl_b = dtb + (size_t)M_ROWS * D_INNER;
    unsigned short* wb_in  = xdbl_b + (size_t)M_ROWS * XPAD;
    unsigned short* wb_out = wb_in + (size_t)NLAYERS * 2 * D_INNER * D_MODEL;
    unsigned short* wb_fc  = wb_out + (size_t)NLAYERS * D_MODEL * D_INNER;
    unsigned short* wb_x   = wb_fc + (size_t)VOCAB * D_MODEL;
    unsigned short* wb_dt  = wb_x + (size_t)NLAYERS * XPAD * D_INNER;

    // ---- all weight casts in ONE launch ----
    cast_all<<<(CAST_TOT + 255) / 256, 256, 0, stream>>>(
        in_proj, out_proj, fc_w, dt_w, x_proj, wb_in, wb_out, wb_fc, wb_dt, wb_x);

    // ---- embedding (fp32 + bf16) ----
    gather_kernel<<<M_ROWS, 256, 0, stream>>>(ids, embed, x, xb);

    for (int i = 0; i < NLAYERS; ++i) {
        const unsigned short* W_in_b  = wb_in + (size_t)i * 2 * D_INNER * D_MODEL;
        const unsigned short* W_out_b = wb_out + (size_t)i * D_MODEL * D_INNER;
        const unsigned short* W_x_b   = wb_x + (size_t)i * XPAD * D_INNER;
        const unsigned short* W_dt_b  = wb_dt + (size_t)i * D_INNER * DT_RANK;
        const float* cw    = conv_w + (size_t)i * D_INNER * 4;
        const float* cb    = conv_b + (size_t)i * D_INNER;
        const float* b_dt  = dt_b + (size_t)i * D_INNER;
        const float* Al    = A_log + (size_t)i * D_INNER * D_STATE;
        const float* Dl    = Dp + (size_t)i * D_INNER;
        const float* g     = ln_g + (size_t)i * D_MODEL;
        const float* bb    = ln_b + (size_t)i * D_MODEL;

        // xz(bf16) = x @ in_proj^T   (2048 x 4096, K=1024)   grid 16x32
        gemm_bf16_nt<1><<<dim3(M_ROWS / 128, 2 * D_INNER / 128), 256, 0, stream>>>(
            xb, D_MODEL, W_in_b, D_MODEL, xzb, 2 * D_INNER, D_MODEL, nullptr);

        // xc(bf16) = silu(conv(xz[:, :2048]) + cb)
        conv_silu_kernel<<<(M_ROWS * D_INNER) / 256, 256, 0, stream>>>(xzb, cw, cb, xcb);

        // x_dbl partials: (2048 x 128, K=2048 split XSK x 128)  grid 16x1x16
        gemm_bf16_nt<0><<<dim3(M_ROWS / 128, 1, XSK), 256, 0, stream>>>(
            xcb, D_INNER, W_x_b, D_INNER, xpart, XPAD, D_INNER / XSK, nullptr);
        reduce_xdbl<<<(M_ROWS * XPAD / 4) / 256, 256, 0, stream>>>(xpart, xdbl, xdbl_b);

        // dt(bf16) = softplus(x_dbl[:, :64] @ dt_w^T + b_dt)  (2048x2048, K=64) grid 16x16
        gemm_bf16_nt<3><<<dim3(M_ROWS / 128, D_INNER / 128), 256, 0, stream>>>(
            xdbl_b, XPAD, W_dt_b, DT_RANK, dtb, D_INNER, DT_RANK, b_dt);

        // chunk-parallel scan -> yb (bf16)
        scan_partial<<<BATCH * NC * (D_INNER / 256), 256, 0, stream>>>(
            dtb, xdbl, xcb, Al, Hbuf, Pbuf);
        scan_combine<<<(BATCH * D_STATE * D_INNER) / 256, 256, 0, stream>>>(Hbuf, Pbuf);
        scan_final<<<BATCH * NC * (D_INNER / 256), 256, 0, stream>>>(
            dtb, xdbl, xcb, xzb, Al, Dl, Pbuf, yb);

        // out_proj partials: (2048 x 1024, K=2048 split 2 x 1024)  grid 16x8x2
        gemm_bf16_nt<0><<<dim3(M_ROWS / 128, D_MODEL / 128, OSK), 256, 0, stream>>>(
            yb, D_INNER, W_out_b, D_INNER, opart, D_MODEL, D_INNER / OSK, nullptr);

        // x = LN(opart0 + opart1 + x)  (fp32 + bf16)
        ln_kernel<2><<<M_ROWS, 256, 0, stream>>>(
            opart, opart + (size_t)M_ROWS * D_MODEL, x, x, xb, g, bb);
    }

    // final LN -> tmp + xb
    ln_kernel<0><<<M_ROWS, 256, 0, stream>>>(nullptr, nullptr, x, tmp, xb, fn_g, fn_b);

    // logits = xf @ fc_w^T + fc_b   (2048 x 32000, K=1024)  8-phase 256² grid 8x125
    gemm_bf16_8ph<<<dim3(M_ROWS / 256, VOCAB / 256), 512, 0, stream>>>(
        xb, D_MODEL, wb_fc, D_MODEL, logits, VOCAB, D_MODEL, fc_b);
}